// Round 4
// baseline (675.255 us; speedup 1.0000x reference)
//
#include <hip/hip_runtime.h>
#include <math.h>

#define HID 32
#define HOR 12
#define NBLK 256          // edge-chunk blocks for count/scatter
#define BSH 6             // 64 nodes per bucket
#define BNODES 64
#define MAXBK 1024        // max buckets (requires N < 65536)

__device__ __forceinline__ float sigmoidf_(float x) { return 1.0f / (1.0f + expf(-x)); }

// K1: per-chunk histograms by src-bucket and dst-bucket (LDS atomics only)
__global__ __launch_bounds__(256) void k_count(const int* __restrict__ src,
    const int* __restrict__ dst, int E, int chunk, int nbk,
    int* __restrict__ histS, int* __restrict__ histD) {
    __shared__ int hs[MAXBK], hd[MAXBK];
    int t = threadIdx.x;
    for (int c = t; c < nbk; c += 256) { hs[c] = 0; hd[c] = 0; }
    __syncthreads();
    int beg = blockIdx.x * chunk, end = min(beg + chunk, E);
    for (int i = beg + t; i < end; i += 256) {
        atomicAdd(&hs[src[i] >> BSH], 1);
        atomicAdd(&hd[dst[i] >> BSH], 1);
    }
    __syncthreads();
    size_t rb = (size_t)blockIdx.x * nbk;
    for (int c = t; c < nbk; c += 256) { histS[rb + c] = hs[c]; histD[rb + c] = hd[c]; }
}

// K2a: in-place column exclusive prefix over chunk-blocks; emit column totals
__global__ void k_colscan(int* __restrict__ histS, int* __restrict__ histD,
                          int* __restrict__ totS, int* __restrict__ totD, int nbk) {
    int table = blockIdx.x & 1;
    int col = (blockIdx.x >> 1) * 256 + threadIdx.x;
    if (col >= nbk) return;
    int* h  = table ? histD : histS;
    int* tt = table ? totD : totS;
    int run = 0;
    for (int b = 0; b < NBLK; ++b) {
        size_t idx = (size_t)b * nbk + col;   // consecutive cols per wave: coalesced
        int v = h[idx]; h[idx] = run; run += v;
    }
    tt[col] = run;
}

// K2b: exclusive scan of bucket totals -> baseS/baseD (nbk+1 entries each)
__global__ __launch_bounds__(256) void k_bucketbase(const int* __restrict__ totS,
    const int* __restrict__ totD, int* __restrict__ baseS, int* __restrict__ baseD, int nbk) {
    __shared__ int ss[256];
    int t = threadIdx.x;
    for (int table = 0; table < 2; ++table) {
        const int* tot = table ? totD : totS;
        int* base = table ? baseD : baseS;
        int a[4]; int tsum = 0;
        #pragma unroll
        for (int k2 = 0; k2 < 4; ++k2) {
            int i = t * 4 + k2;
            a[k2] = (i < nbk) ? tot[i] : 0;
            tsum += a[k2];
        }
        ss[t] = tsum; __syncthreads();
        for (int off = 1; off < 256; off <<= 1) {
            int v = (t >= off) ? ss[t - off] : 0;
            __syncthreads(); ss[t] += v; __syncthreads();
        }
        int run = ss[t] - tsum;  // exclusive over threads
        #pragma unroll
        for (int k2 = 0; k2 < 4; ++k2) {
            int i = t * 4 + k2;
            if (i <= nbk) base[i] = run;
            run += a[k2];
        }
        __syncthreads();
    }
}

// flag = 1 if any h0 element nonzero
__global__ void k_hflag(const float* __restrict__ h0, int* __restrict__ flag, int total) {
    int i = blockIdx.x * 256 + threadIdx.x;
    float v = (i < total) ? h0[i] : 0.0f;
    if (__ballot(v != 0.0f)) {
        if ((threadIdx.x & 63) == 0) atomicOr(flag, 1);
    }
}

// K3: scatter edges into exact reserved slots; LDS cursors only, plain global stores
__global__ __launch_bounds__(256) void k_scatter2(const int* __restrict__ src,
    const int* __restrict__ dst, const float* __restrict__ w, int E, int chunk, int nbk,
    const int* __restrict__ histS, const int* __restrict__ histD,
    const int* __restrict__ baseS, const int* __restrict__ baseD,
    int2* __restrict__ srcBins, int2* __restrict__ dstBins) {
    __shared__ int curS[MAXBK], curD[MAXBK];
    int t = threadIdx.x;
    size_t rb = (size_t)blockIdx.x * nbk;
    for (int c = t; c < nbk; c += 256) {
        curS[c] = baseS[c] + histS[rb + c];
        curD[c] = baseD[c] + histD[rb + c];
    }
    __syncthreads();
    int beg = blockIdx.x * chunk, end = min(beg + chunk, E);
    for (int i = beg + t; i < end; i += 256) {
        int s = src[i], d = dst[i];
        float wv = w[i];
        int ps = atomicAdd(&curS[s >> BSH], 1);             // LDS RMW
        srcBins[ps] = make_int2(s, __float_as_int(wv));
        int pd = atomicAdd(&curD[d >> BSH], 1);             // LDS RMW
        dstBins[pd] = make_int2(s | ((d & (BNODES - 1)) << 16), __float_as_int(wv));
    }
}

// K4: per src-bucket: deg in LDS (ds_add_f32) -> dinv coalesced
__global__ __launch_bounds__(256) void k_deg(const int2* __restrict__ srcBins,
    const int* __restrict__ baseS, float* __restrict__ dinv, int N) {
    __shared__ float dg[BNODES];
    int t = threadIdx.x, b = blockIdx.x;
    if (t < BNODES) dg[t] = 0.0f;
    __syncthreads();
    int beg = baseS[b], end = baseS[b + 1];
    for (int i = beg + t; i < end; i += 256) {
        int2 r = srcBins[i];
        atomicAdd(&dg[r.x & (BNODES - 1)], __int_as_float(r.y));
    }
    __syncthreads();
    if (t < BNODES) {
        int n = (b << BSH) + t;
        if (n < N) { float s = dg[t]; dinv[n] = (s > 0.0f) ? rsqrtf(s) : 0.0f; }
    }
}

// K6: per dst-bucket: accumulate LX (and LH if h0!=0) in LDS tile, write coalesced.
// 32 lanes = one edge's 32 feats: X row read is one 128B line; ds_add is bank-conflict-free.
__global__ __launch_bounds__(256) void k_acc(const int2* __restrict__ dstBins,
    const int* __restrict__ baseD, const float* __restrict__ dinv,
    const float* __restrict__ X, const float* __restrict__ H0,
    const int* __restrict__ hflag,
    float* __restrict__ LX, float* __restrict__ LH, int N) {
    __shared__ float lx[BNODES * HID], lh[BNODES * HID];
    __shared__ float dvD[BNODES];
    int t = threadIdx.x, b = blockIdx.x;
    for (int i = t; i < BNODES * HID; i += 256) { lx[i] = 0.0f; lh[i] = 0.0f; }
    if (t < BNODES) {
        int n = (b << BSH) + t;
        dvD[t] = (n < N) ? dinv[n] : 0.0f;
    }
    __syncthreads();
    int f = t & 31, g = t >> 5;
    int beg = baseD[b], end = baseD[b + 1];
    bool hf = (*hflag != 0);
    if (hf) {
        for (int i = beg + g; i < end; i += 8) {
            int2 r = dstBins[i];
            int s = r.x & 0xFFFF, dl = r.x >> 16;
            float nw = -__int_as_float(r.y) * dinv[s] * dvD[dl];
            atomicAdd(&lx[(dl << 5) + f], nw * X[(s << 5) + f]);
            atomicAdd(&lh[(dl << 5) + f], nw * H0[(s << 5) + f]);
        }
    } else {
        for (int i = beg + g; i < end; i += 8) {
            int2 r = dstBins[i];
            int s = r.x & 0xFFFF, dl = r.x >> 16;
            float nw = -__int_as_float(r.y) * dinv[s] * dvD[dl];
            atomicAdd(&lx[(dl << 5) + f], nw * X[(s << 5) + f]);
        }
    }
    __syncthreads();
    size_t obase = ((size_t)b << BSH) << 5;
    for (int i = t; i < BNODES * HID; i += 256) {
        int n = (b << BSH) + (i >> 5);
        if (n < N) { LX[obase + i] = lx[i]; LH[obase + i] = lh[i]; }
    }
}

// Per (node n, out-feature j): 4 gates fused LSTM cell
__global__ __launch_bounds__(256) void k_gates(
    const float* __restrict__ X, const float* __restrict__ LX,
    const float* __restrict__ H0, const float* __restrict__ LH,
    const float* __restrict__ C0,
    const float* __restrict__ Wx, const float* __restrict__ bx,
    const float* __restrict__ Wh, const float* __restrict__ bh,
    const float* __restrict__ wc, const float* __restrict__ b,
    float* __restrict__ outH, float* __restrict__ outC, int N) {
    int tid = blockIdx.x * 256 + threadIdx.x;
    int n = tid >> 5;
    int j = tid & 31;
    if (n >= N) return;

    int base = n << 5;
    float xk  = X[base + j];
    float lxk = LX[base + j];
    float hk  = H0[base + j];
    float lhk = LH[base + j];

    float pre0 = bx[0 * HID + j] + bh[0 * HID + j] + b[0 * HID + j];
    float pre1 = bx[1 * HID + j] + bh[1 * HID + j] + b[1 * HID + j];
    float pre2 = bx[2 * HID + j] + bh[2 * HID + j] + b[2 * HID + j];
    float pre3 = bx[3 * HID + j] + bh[3 * HID + j] + b[3 * HID + j];

    #pragma unroll 8
    for (int k = 0; k < HID; ++k) {
        float xv  = __shfl(xk, k, 32);
        float lxv = __shfl(lxk, k, 32);
        float hv  = __shfl(hk, k, 32);
        float lhv = __shfl(lhk, k, 32);
        int row = k * HID + j;
        pre0 += xv * Wx[0 * 2048 + row] + lxv * Wx[0 * 2048 + 1024 + row]
              + hv * Wh[0 * 2048 + row] + lhv * Wh[0 * 2048 + 1024 + row];
        pre1 += xv * Wx[1 * 2048 + row] + lxv * Wx[1 * 2048 + 1024 + row]
              + hv * Wh[1 * 2048 + row] + lhv * Wh[1 * 2048 + 1024 + row];
        pre2 += xv * Wx[2 * 2048 + row] + lxv * Wx[2 * 2048 + 1024 + row]
              + hv * Wh[2 * 2048 + row] + lhv * Wh[2 * 2048 + 1024 + row];
        pre3 += xv * Wx[3 * 2048 + row] + lxv * Wx[3 * 2048 + 1024 + row]
              + hv * Wh[3 * 2048 + row] + lhv * Wh[3 * 2048 + 1024 + row];
    }

    float c0v = C0[base + j];
    float I  = sigmoidf_(pre0 + wc[0 * HID + j] * c0v);
    float Fg = sigmoidf_(pre1 + wc[1 * HID + j] * c0v);
    float T  = tanhf(pre2);
    float C  = Fg * c0v + I * T;
    float O  = sigmoidf_(pre3 + wc[2 * HID + j] * C);
    float H  = O * tanhf(C);

    outH[base + j] = H;
    outC[base + j] = C;
}

// h[n,t] = b_lin[t] + sum_k relu(H[n,k]) * W_lin[k,t]
__global__ void k_head(const float* __restrict__ H, const float* __restrict__ Wl,
                       const float* __restrict__ bl, float* __restrict__ hout, int N) {
    int tid = blockIdx.x * 256 + threadIdx.x;
    int n = tid / HOR;
    int t = tid - n * HOR;
    if (n >= N) return;
    float acc = bl[t];
    #pragma unroll
    for (int k = 0; k < HID; ++k) {
        float v = H[(n << 5) + k];
        acc += fmaxf(v, 0.0f) * Wl[k * HOR + t];
    }
    hout[n * HOR + t] = acc;
}

extern "C" void kernel_launch(void* const* d_in, const int* in_sizes, int n_in,
                              void* d_out, int out_size, void* d_ws, size_t ws_size,
                              hipStream_t stream) {
    const float* x  = (const float*)d_in[0];
    const int*   ei = (const int*)d_in[1];
    const float* ew = (const float*)d_in[2];
    const float* Wx = (const float*)d_in[3];
    const float* bx = (const float*)d_in[4];
    const float* Wh = (const float*)d_in[5];
    const float* bh = (const float*)d_in[6];
    const float* wc = (const float*)d_in[7];
    const float* b  = (const float*)d_in[8];
    const float* Wl = (const float*)d_in[9];
    const float* bl = (const float*)d_in[10];
    const float* h0 = (const float*)d_in[11];
    const float* c0 = (const float*)d_in[12];

    int N = in_sizes[0] / HID;      // x is (N,1,32)
    int E = in_sizes[2];            // edge_weight is (E,)
    const int* src = ei;
    const int* dst = ei + E;
    int nbk = (N + BNODES - 1) >> BSH;          // 782 for N=50000 (< MAXBK)
    int chunk = (E + NBLK - 1) / NBLK;

    // workspace (int units):
    // [dstBins 2E][srcBins region: max(2E, 2*N*32) — srcBins aliased by LX/LH]
    // [histS NBLK*nbk][histD NBLK*nbk][totS MAXBK][totD MAXBK]
    // [baseS MAXBK+1][baseD MAXBK+1][dinv N][flag 1]
    int* wsi = (int*)d_ws;
    size_t regionB = (size_t)2 * E;                  // srcBins size
    size_t regionL = (size_t)2 * N * HID;            // LX+LH size
    size_t region  = regionB > regionL ? regionB : regionL;

    int2*  dstBins = (int2*)wsi;
    int2*  srcBins = (int2*)(wsi + (size_t)2 * E);
    float* LX      = (float*)srcBins;                // aliases srcBins (dead after k_deg)
    float* LH      = LX + (size_t)N * HID;
    int*   histS   = wsi + (size_t)2 * E + region;
    int*   histD   = histS + (size_t)NBLK * nbk;
    int*   totS    = histD + (size_t)NBLK * nbk;
    int*   totD    = totS + MAXBK;
    int*   baseS   = totD + MAXBK;
    int*   baseD   = baseS + (MAXBK + 1);
    float* dinv    = (float*)(baseD + (MAXBK + 1));
    int*   flag    = (int*)(dinv + N);

    float* hOut = (float*)d_out;            // (N,12)
    float* HOut = hOut + (size_t)N * HOR;   // (N,32)
    float* COut = HOut + (size_t)N * HID;   // (N,32)

    hipMemsetAsync(flag, 0, sizeof(int), stream);

    k_count<<<NBLK, 256, 0, stream>>>(src, dst, E, chunk, nbk, histS, histD);
    k_colscan<<<2 * ((nbk + 255) / 256), 256, 0, stream>>>(histS, histD, totS, totD, nbk);
    k_bucketbase<<<1, 256, 0, stream>>>(totS, totD, baseS, baseD, nbk);
    k_hflag<<<(N * HID + 255) / 256, 256, 0, stream>>>(h0, flag, N * HID);

    k_scatter2<<<NBLK, 256, 0, stream>>>(src, dst, ew, E, chunk, nbk,
                                         histS, histD, baseS, baseD, srcBins, dstBins);

    k_deg<<<nbk, 256, 0, stream>>>(srcBins, baseS, dinv, N);

    k_acc<<<nbk, 256, 0, stream>>>(dstBins, baseD, dinv, x, h0, flag, LX, LH, N);

    k_gates<<<(N * HID + 255) / 256, 256, 0, stream>>>(x, LX, h0, LH, c0,
                                                       Wx, bx, Wh, bh, wc, b,
                                                       HOut, COut, N);

    k_head<<<(N * HOR + 255) / 256, 256, 0, stream>>>(HOut, Wl, bl, hOut, N);
}

// Round 5
// 650.021 us; speedup vs baseline: 1.0388x; 1.0388x over previous
//
#include <hip/hip_runtime.h>
#include <math.h>

#define HID 32
#define HOR 12
#define NBLK 128          // edge-chunk blocks for count/scatter
#define BSH 5             // 32 nodes per bucket
#define BNODES 32
#define MAXBK 2048        // max buckets (requires N <= 65536 and nbk <= MAXBK)

__device__ __forceinline__ float sigmoidf_(float x) { return 1.0f / (1.0f + expf(-x)); }

// K1: per-chunk histograms by src-bucket and dst-bucket (LDS atomics only)
__global__ __launch_bounds__(256) void k_count(const int* __restrict__ src,
    const int* __restrict__ dst, int E, int chunk, int nbk,
    int* __restrict__ histS, int* __restrict__ histD) {
    __shared__ int hs[MAXBK], hd[MAXBK];
    int t = threadIdx.x;
    for (int c = t; c < nbk; c += 256) { hs[c] = 0; hd[c] = 0; }
    __syncthreads();
    int beg = blockIdx.x * chunk, end = min(beg + chunk, E);
    for (int i = beg + t; i < end; i += 256) {
        atomicAdd(&hs[src[i] >> BSH], 1);
        atomicAdd(&hd[dst[i] >> BSH], 1);
    }
    __syncthreads();
    size_t rb = (size_t)blockIdx.x * nbk;
    for (int c = t; c < nbk; c += 256) { histS[rb + c] = hs[c]; histD[rb + c] = hd[c]; }
}

// K2a: in-place column exclusive prefix over chunk-blocks; emit column totals
__global__ void k_colscan(int* __restrict__ histS, int* __restrict__ histD,
                          int* __restrict__ totS, int* __restrict__ totD, int nbk) {
    int table = blockIdx.x & 1;
    int col = (blockIdx.x >> 1) * 256 + threadIdx.x;
    if (col >= nbk) return;
    int* h  = table ? histD : histS;
    int* tt = table ? totD : totS;
    int run = 0;
    for (int b = 0; b < NBLK; ++b) {
        size_t idx = (size_t)b * nbk + col;   // consecutive cols per wave: coalesced
        int v = h[idx]; h[idx] = run; run += v;
    }
    tt[col] = run;
}

// K2b: exclusive scan of bucket totals -> baseS/baseD (nbk+1 entries each)
__global__ __launch_bounds__(256) void k_bucketbase(const int* __restrict__ totS,
    const int* __restrict__ totD, int* __restrict__ baseS, int* __restrict__ baseD, int nbk) {
    __shared__ int ss[256];
    int t = threadIdx.x;
    for (int table = 0; table < 2; ++table) {
        const int* tot = table ? totD : totS;
        int* base = table ? baseD : baseS;
        int a[8]; int tsum = 0;
        #pragma unroll
        for (int k2 = 0; k2 < 8; ++k2) {
            int i = t * 8 + k2;
            a[k2] = (i < nbk) ? tot[i] : 0;
            tsum += a[k2];
        }
        ss[t] = tsum; __syncthreads();
        for (int off = 1; off < 256; off <<= 1) {
            int v = (t >= off) ? ss[t - off] : 0;
            __syncthreads(); ss[t] += v; __syncthreads();
        }
        int run = ss[t] - tsum;  // exclusive over threads
        #pragma unroll
        for (int k2 = 0; k2 < 8; ++k2) {
            int i = t * 8 + k2;
            if (i <= nbk) base[i] = run;
            run += a[k2];
        }
        __syncthreads();
    }
}

// flag = 1 if any h0 element nonzero
__global__ void k_hflag(const float* __restrict__ h0, int* __restrict__ flag, int total) {
    int i = blockIdx.x * 256 + threadIdx.x;
    float v = (i < total) ? h0[i] : 0.0f;
    if (__ballot(v != 0.0f)) {
        if ((threadIdx.x & 63) == 0) atomicOr(flag, 1);
    }
}

// K3: scatter edges into exact reserved slots; LDS cursors only, plain global stores
__global__ __launch_bounds__(256) void k_scatter2(const int* __restrict__ src,
    const int* __restrict__ dst, const float* __restrict__ w, int E, int chunk, int nbk,
    const int* __restrict__ histS, const int* __restrict__ histD,
    const int* __restrict__ baseS, const int* __restrict__ baseD,
    int2* __restrict__ srcBins, int2* __restrict__ dstBins) {
    __shared__ int curS[MAXBK], curD[MAXBK];
    int t = threadIdx.x;
    size_t rb = (size_t)blockIdx.x * nbk;
    for (int c = t; c < nbk; c += 256) {
        curS[c] = baseS[c] + histS[rb + c];
        curD[c] = baseD[c] + histD[rb + c];
    }
    __syncthreads();
    int beg = blockIdx.x * chunk, end = min(beg + chunk, E);
    for (int i = beg + t; i < end; i += 256) {
        int s = src[i], d = dst[i];
        float wv = w[i];
        int ps = atomicAdd(&curS[s >> BSH], 1);             // LDS RMW
        srcBins[ps] = make_int2(s, __float_as_int(wv));
        int pd = atomicAdd(&curD[d >> BSH], 1);             // LDS RMW
        dstBins[pd] = make_int2(s | ((d & (BNODES - 1)) << 16), __float_as_int(wv));
    }
}

// K4: per src-bucket: deg in LDS (ds_add_f32) -> dinv coalesced
__global__ __launch_bounds__(256) void k_deg(const int2* __restrict__ srcBins,
    const int* __restrict__ baseS, float* __restrict__ dinv, int N) {
    __shared__ float dg[BNODES];
    int t = threadIdx.x, b = blockIdx.x;
    if (t < BNODES) dg[t] = 0.0f;
    __syncthreads();
    int beg = baseS[b], end = baseS[b + 1];
    for (int i = beg + t; i < end; i += 256) {
        int2 r = srcBins[i];
        atomicAdd(&dg[r.x & (BNODES - 1)], __int_as_float(r.y));
    }
    __syncthreads();
    if (t < BNODES) {
        int n = (b << BSH) + t;
        if (n < N) { float s = dg[t]; dinv[n] = (s > 0.0f) ? rsqrtf(s) : 0.0f; }
    }
}

// K5: per dst-bucket: fold nw = -w*dinv[s]*dinv[d] into dstBins.y (streaming, high ILP)
__global__ __launch_bounds__(256) void k_nw2(int2* __restrict__ dstBins,
    const int* __restrict__ baseD, const float* __restrict__ dinv, int N) {
    __shared__ float dvD[BNODES];
    int t = threadIdx.x, b = blockIdx.x;
    if (t < BNODES) {
        int n = (b << BSH) + t;
        dvD[t] = (n < N) ? dinv[n] : 0.0f;
    }
    __syncthreads();
    int beg = baseD[b], end = baseD[b + 1];
    for (int i = beg + t; i < end; i += 256) {
        int2 r = dstBins[i];
        int s = r.x & 0xFFFF, dl = r.x >> 16;
        float nw = -__int_as_float(r.y) * dinv[s] * dvD[dl];
        dstBins[i] = make_int2(r.x, __float_as_int(nw));
    }
}

// K6: per dst-bucket: accumulate LX (and LH if h0!=0) in LDS tile, write coalesced.
// 32 lanes = one edge's 32 feats (one 128B line); ds_add is 2-way aliased (free).
// Manual 4x unroll: 8 independent X-row loads in flight per wave.
__global__ __launch_bounds__(256) void k_acc(const int2* __restrict__ dstBins,
    const int* __restrict__ baseD,
    const float* __restrict__ X, const float* __restrict__ H0,
    const int* __restrict__ hflag,
    float* __restrict__ LX, float* __restrict__ LH, int N) {
    __shared__ float lx[BNODES * HID], lh[BNODES * HID];
    int t = threadIdx.x, b = blockIdx.x;
    for (int i = t; i < BNODES * HID; i += 256) { lx[i] = 0.0f; lh[i] = 0.0f; }
    __syncthreads();
    int f = t & 31, g = t >> 5;
    int beg = baseD[b], end = baseD[b + 1];
    bool hf = (*hflag != 0);
    int i = beg + g;
    if (hf) {
        for (; i + 24 < end; i += 32) {
            int2 r0 = dstBins[i];
            int2 r1 = dstBins[i + 8];
            int2 r2 = dstBins[i + 16];
            int2 r3 = dstBins[i + 24];
            float v0 = __int_as_float(r0.y) * X[((r0.x & 0xFFFF) << 5) + f];
            float v1 = __int_as_float(r1.y) * X[((r1.x & 0xFFFF) << 5) + f];
            float v2 = __int_as_float(r2.y) * X[((r2.x & 0xFFFF) << 5) + f];
            float v3 = __int_as_float(r3.y) * X[((r3.x & 0xFFFF) << 5) + f];
            float u0 = __int_as_float(r0.y) * H0[((r0.x & 0xFFFF) << 5) + f];
            float u1 = __int_as_float(r1.y) * H0[((r1.x & 0xFFFF) << 5) + f];
            float u2 = __int_as_float(r2.y) * H0[((r2.x & 0xFFFF) << 5) + f];
            float u3 = __int_as_float(r3.y) * H0[((r3.x & 0xFFFF) << 5) + f];
            atomicAdd(&lx[((r0.x >> 16) << 5) + f], v0);
            atomicAdd(&lx[((r1.x >> 16) << 5) + f], v1);
            atomicAdd(&lx[((r2.x >> 16) << 5) + f], v2);
            atomicAdd(&lx[((r3.x >> 16) << 5) + f], v3);
            atomicAdd(&lh[((r0.x >> 16) << 5) + f], u0);
            atomicAdd(&lh[((r1.x >> 16) << 5) + f], u1);
            atomicAdd(&lh[((r2.x >> 16) << 5) + f], u2);
            atomicAdd(&lh[((r3.x >> 16) << 5) + f], u3);
        }
        for (; i < end; i += 8) {
            int2 r = dstBins[i];
            float nw = __int_as_float(r.y);
            atomicAdd(&lx[((r.x >> 16) << 5) + f], nw * X[((r.x & 0xFFFF) << 5) + f]);
            atomicAdd(&lh[((r.x >> 16) << 5) + f], nw * H0[((r.x & 0xFFFF) << 5) + f]);
        }
    } else {
        for (; i + 24 < end; i += 32) {
            int2 r0 = dstBins[i];
            int2 r1 = dstBins[i + 8];
            int2 r2 = dstBins[i + 16];
            int2 r3 = dstBins[i + 24];
            float v0 = __int_as_float(r0.y) * X[((r0.x & 0xFFFF) << 5) + f];
            float v1 = __int_as_float(r1.y) * X[((r1.x & 0xFFFF) << 5) + f];
            float v2 = __int_as_float(r2.y) * X[((r2.x & 0xFFFF) << 5) + f];
            float v3 = __int_as_float(r3.y) * X[((r3.x & 0xFFFF) << 5) + f];
            atomicAdd(&lx[((r0.x >> 16) << 5) + f], v0);
            atomicAdd(&lx[((r1.x >> 16) << 5) + f], v1);
            atomicAdd(&lx[((r2.x >> 16) << 5) + f], v2);
            atomicAdd(&lx[((r3.x >> 16) << 5) + f], v3);
        }
        for (; i < end; i += 8) {
            int2 r = dstBins[i];
            atomicAdd(&lx[((r.x >> 16) << 5) + f],
                      __int_as_float(r.y) * X[((r.x & 0xFFFF) << 5) + f]);
        }
    }
    __syncthreads();
    size_t obase = ((size_t)b << BSH) << 5;
    for (int k = t; k < BNODES * HID; k += 256) {
        int n = (b << BSH) + (k >> 5);
        if (n < N) { LX[obase + k] = lx[k]; LH[obase + k] = lh[k]; }
    }
}

// Per (node n, out-feature j): 4 gates fused LSTM cell
__global__ __launch_bounds__(256) void k_gates(
    const float* __restrict__ X, const float* __restrict__ LX,
    const float* __restrict__ H0, const float* __restrict__ LH,
    const float* __restrict__ C0,
    const float* __restrict__ Wx, const float* __restrict__ bx,
    const float* __restrict__ Wh, const float* __restrict__ bh,
    const float* __restrict__ wc, const float* __restrict__ b,
    float* __restrict__ outH, float* __restrict__ outC, int N) {
    int tid = blockIdx.x * 256 + threadIdx.x;
    int n = tid >> 5;
    int j = tid & 31;
    if (n >= N) return;

    int base = n << 5;
    float xk  = X[base + j];
    float lxk = LX[base + j];
    float hk  = H0[base + j];
    float lhk = LH[base + j];

    float pre0 = bx[0 * HID + j] + bh[0 * HID + j] + b[0 * HID + j];
    float pre1 = bx[1 * HID + j] + bh[1 * HID + j] + b[1 * HID + j];
    float pre2 = bx[2 * HID + j] + bh[2 * HID + j] + b[2 * HID + j];
    float pre3 = bx[3 * HID + j] + bh[3 * HID + j] + b[3 * HID + j];

    #pragma unroll 8
    for (int k = 0; k < HID; ++k) {
        float xv  = __shfl(xk, k, 32);
        float lxv = __shfl(lxk, k, 32);
        float hv  = __shfl(hk, k, 32);
        float lhv = __shfl(lhk, k, 32);
        int row = k * HID + j;
        pre0 += xv * Wx[0 * 2048 + row] + lxv * Wx[0 * 2048 + 1024 + row]
              + hv * Wh[0 * 2048 + row] + lhv * Wh[0 * 2048 + 1024 + row];
        pre1 += xv * Wx[1 * 2048 + row] + lxv * Wx[1 * 2048 + 1024 + row]
              + hv * Wh[1 * 2048 + row] + lhv * Wh[1 * 2048 + 1024 + row];
        pre2 += xv * Wx[2 * 2048 + row] + lxv * Wx[2 * 2048 + 1024 + row]
              + hv * Wh[2 * 2048 + row] + lhv * Wh[2 * 2048 + 1024 + row];
        pre3 += xv * Wx[3 * 2048 + row] + lxv * Wx[3 * 2048 + 1024 + row]
              + hv * Wh[3 * 2048 + row] + lhv * Wh[3 * 2048 + 1024 + row];
    }

    float c0v = C0[base + j];
    float I  = sigmoidf_(pre0 + wc[0 * HID + j] * c0v);
    float Fg = sigmoidf_(pre1 + wc[1 * HID + j] * c0v);
    float T  = tanhf(pre2);
    float C  = Fg * c0v + I * T;
    float O  = sigmoidf_(pre3 + wc[2 * HID + j] * C);
    float H  = O * tanhf(C);

    outH[base + j] = H;
    outC[base + j] = C;
}

// h[n,t] = b_lin[t] + sum_k relu(H[n,k]) * W_lin[k,t]
__global__ void k_head(const float* __restrict__ H, const float* __restrict__ Wl,
                       const float* __restrict__ bl, float* __restrict__ hout, int N) {
    int tid = blockIdx.x * 256 + threadIdx.x;
    int n = tid / HOR;
    int t = tid - n * HOR;
    if (n >= N) return;
    float acc = bl[t];
    #pragma unroll
    for (int k = 0; k < HID; ++k) {
        float v = H[(n << 5) + k];
        acc += fmaxf(v, 0.0f) * Wl[k * HOR + t];
    }
    hout[n * HOR + t] = acc;
}

extern "C" void kernel_launch(void* const* d_in, const int* in_sizes, int n_in,
                              void* d_out, int out_size, void* d_ws, size_t ws_size,
                              hipStream_t stream) {
    const float* x  = (const float*)d_in[0];
    const int*   ei = (const int*)d_in[1];
    const float* ew = (const float*)d_in[2];
    const float* Wx = (const float*)d_in[3];
    const float* bx = (const float*)d_in[4];
    const float* Wh = (const float*)d_in[5];
    const float* bh = (const float*)d_in[6];
    const float* wc = (const float*)d_in[7];
    const float* b  = (const float*)d_in[8];
    const float* Wl = (const float*)d_in[9];
    const float* bl = (const float*)d_in[10];
    const float* h0 = (const float*)d_in[11];
    const float* c0 = (const float*)d_in[12];

    int N = in_sizes[0] / HID;      // x is (N,1,32)
    int E = in_sizes[2];            // edge_weight is (E,)
    const int* src = ei;
    const int* dst = ei + E;
    int nbk = (N + BNODES - 1) >> BSH;          // 1563 for N=50000 (< MAXBK)
    int chunk = (E + NBLK - 1) / NBLK;

    // workspace (int units):
    // [dstBins 2E][srcBins region: max(2E, 2*N*32) — srcBins aliased by LX/LH]
    // [histS NBLK*nbk][histD NBLK*nbk][totS MAXBK][totD MAXBK]
    // [baseS MAXBK+1][baseD MAXBK+1][dinv N][flag 1]
    int* wsi = (int*)d_ws;
    size_t regionB = (size_t)2 * E;                  // srcBins size
    size_t regionL = (size_t)2 * N * HID;            // LX+LH size
    size_t region  = regionB > regionL ? regionB : regionL;

    int2*  dstBins = (int2*)wsi;
    int2*  srcBins = (int2*)(wsi + (size_t)2 * E);
    float* LX      = (float*)srcBins;                // aliases srcBins (dead after k_deg)
    float* LH      = LX + (size_t)N * HID;
    int*   histS   = wsi + (size_t)2 * E + region;
    int*   histD   = histS + (size_t)NBLK * nbk;
    int*   totS    = histD + (size_t)NBLK * nbk;
    int*   totD    = totS + MAXBK;
    int*   baseS   = totD + MAXBK;
    int*   baseD   = baseS + (MAXBK + 1);
    float* dinv    = (float*)(baseD + (MAXBK + 1));
    int*   flag    = (int*)(dinv + N);

    float* hOut = (float*)d_out;            // (N,12)
    float* HOut = hOut + (size_t)N * HOR;   // (N,32)
    float* COut = HOut + (size_t)N * HID;   // (N,32)

    hipMemsetAsync(flag, 0, sizeof(int), stream);

    k_count<<<NBLK, 256, 0, stream>>>(src, dst, E, chunk, nbk, histS, histD);
    k_colscan<<<2 * ((nbk + 255) / 256), 256, 0, stream>>>(histS, histD, totS, totD, nbk);
    k_bucketbase<<<1, 256, 0, stream>>>(totS, totD, baseS, baseD, nbk);
    k_hflag<<<(N * HID + 255) / 256, 256, 0, stream>>>(h0, flag, N * HID);

    k_scatter2<<<NBLK, 256, 0, stream>>>(src, dst, ew, E, chunk, nbk,
                                         histS, histD, baseS, baseD, srcBins, dstBins);

    k_deg<<<nbk, 256, 0, stream>>>(srcBins, baseS, dinv, N);

    k_nw2<<<nbk, 256, 0, stream>>>(dstBins, baseD, dinv, N);

    k_acc<<<nbk, 256, 0, stream>>>(dstBins, baseD, x, h0, flag, LX, LH, N);

    k_gates<<<(N * HID + 255) / 256, 256, 0, stream>>>(x, LX, h0, LH, c0,
                                                       Wx, bx, Wh, bh, wc, b,
                                                       HOut, COut, N);

    k_head<<<(N * HOR + 255) / 256, 256, 0, stream>>>(HOut, Wl, bl, hOut, N);
}